// Round 1
// 435.789 us; speedup vs baseline: 1.1015x; 1.1015x over previous
//
#include <hip/hip_runtime.h>
#include <math.h>

// MessagePassingUnitGatingWithRelnessLogits fused kernel, MI355X (gfx950).
// N=32768 rows; D=1024 (paired=2048); A=256; FD=64; F8=8.
// Block = 16 rows, 256 threads (4 waves).
// v2: no activation LDS staging. Phase 1 = LN stats + aux gate only.
//     Phase 2 = k-split MFMA with global fragment-layout reloads (L2-hot),
//     normalize-in-registers, 17.5 KB LDS partial reduce.
//     LDS 64KB -> 17.5KB lifts occupancy 8 -> 16 waves/CU (VGPR-limited).

#define EPS_LN 1e-5f

typedef __attribute__((ext_vector_type(8))) short short8;   // 8 x bf16 (4 VGPRs)
typedef __attribute__((ext_vector_type(4))) float f32x4;    // MFMA accumulator

__device__ __forceinline__ unsigned short f2bf(float f) {
  unsigned int u = __float_as_uint(f);
  u += 0x7FFFu + ((u >> 16) & 1u);      // round-to-nearest-even
  return (unsigned short)(u >> 16);
}

__device__ __forceinline__ float wsum64(float v) {
  v += __shfl_xor(v, 32);
  v += __shfl_xor(v, 16);
  v += __shfl_xor(v, 8);
  v += __shfl_xor(v, 4);
  v += __shfl_xor(v, 2);
  v += __shfl_xor(v, 1);
  return v;
}

__device__ __forceinline__ float sigmoidf_(float x) {
  return 1.0f / (1.0f + __expf(-x));
}

// reverse_sigmoid forward: clip to [0.001,0.999], then logit
__device__ __forceinline__ float rsigf(float x) {
  float y = fminf(fmaxf(x, 0.001f), 0.999f);
  return logf(y) - log1pf(-y);
}

// normalize one element: relu -> LN affine -> relu -> bf16
__device__ __forceinline__ short nrm1(float x, float g, float b,
                                      float rs, float nmr) {
  float t = fmaxf(x, 0.f);
  float n = fmaf(t, rs, nmr);           // (t - mu) * rstd
  float z = fmaxf(fmaf(n, g, b), 0.f);
  return (short)f2bf(z);
}

// ---------------------------------------------------------------------------
// Prep: W [2048][64] fp32 -> bf16 B-fragments in MFMA operand order.
// Layout: frag[((ntile*64 + kb)*64 + lane)*8 + j] = bf16(W[k][f]),
//   f = ntile*16 + (lane&15), k = kb*32 + (lane>>4)*8 + j.
// grid = 256 blocks (ntile*64+kb) x 64 threads.
// ---------------------------------------------------------------------------
__global__ void prep_wfrag(const float* __restrict__ W,
                           unsigned short* __restrict__ wfrag) {
  const int lane = threadIdx.x;
  const int b = blockIdx.x;
  const int ntile = b >> 6;
  const int kb = b & 63;
  const int f = (ntile << 4) + (lane & 15);
  const int kbase = (kb << 5) + ((lane >> 4) << 3);
  unsigned short tmp[8];
#pragma unroll
  for (int j = 0; j < 8; ++j) tmp[j] = f2bf(W[(size_t)(kbase + j) * 64 + f]);
  ushort4* dst = reinterpret_cast<ushort4*>(wfrag + (((size_t)b * 64 + lane) << 3));
  dst[0] = make_ushort4(tmp[0], tmp[1], tmp[2], tmp[3]);
  dst[1] = make_ushort4(tmp[4], tmp[5], tmp[6], tmp[7]);
}

// ---------------------------------------------------------------------------
// Main fused kernel.
// ---------------------------------------------------------------------------
__global__ void __launch_bounds__(256, 4) fused_main(
    const float* __restrict__ unary, const float* __restrict__ pair,
    const float* __restrict__ aux, const float* __restrict__ auxw,
    const float* __restrict__ ln_g, const float* __restrict__ ln_b,
    const float* __restrict__ b_lin,
    const float* __restrict__ ln_ag, const float* __restrict__ ln_ab,
    const float* __restrict__ W_aux, const float* __restrict__ b_aux,
    const float* __restrict__ gw, const float* __restrict__ agw,
    const unsigned short* __restrict__ wfrag,
    float* __restrict__ out, float* __restrict__ out_g) {
  // Cross-wave f32 partial tiles [wave][row][f], f-stride 68 to de-stride banks.
  __shared__ float part[4][16][68];     // 17408 B
  __shared__ float stat_mu[16];
  __shared__ float stat_rs[16];

  const int tid = threadIdx.x;
  const int w = tid >> 6;     // wave 0..3
  const int lane = tid & 63;
  const int base = blockIdx.x << 4;

  float auxg0 = 0.f, auxg1 = 0.f, auxg2 = 0.f, auxg3 = 0.f;

  // Hoisted row-invariant aux params.
  const float4 agv4 = reinterpret_cast<const float4*>(ln_ag)[lane];
  const float4 abv4 = reinterpret_cast<const float4*>(ln_ab)[lane];
  const float bauxl = b_aux[lane & 7];

  // ------------- phase 1: LN stats (no staging) + aux gate per row ---------
#pragma unroll
  for (int i = 0; i < 4; ++i) {
    const int rl = (w << 2) + i;         // local row 0..15
    const int row = base + rl;

    const float4* u4 = reinterpret_cast<const float4*>(unary + (size_t)row * 1024);
    const float4* p4 = reinterpret_cast<const float4*>(pair + (size_t)row * 1024);
    float s = 0.f, sq = 0.f;
#pragma unroll
    for (int j = 0; j < 4; ++j) {
      float4 uv = u4[lane + 64 * j];
      float4 pv = p4[lane + 64 * j];
      uv.x = fmaxf(uv.x, 0.f); uv.y = fmaxf(uv.y, 0.f);
      uv.z = fmaxf(uv.z, 0.f); uv.w = fmaxf(uv.w, 0.f);
      pv.x = fmaxf(pv.x, 0.f); pv.y = fmaxf(pv.y, 0.f);
      pv.z = fmaxf(pv.z, 0.f); pv.w = fmaxf(pv.w, 0.f);
      s += uv.x + uv.y + uv.z + uv.w;
      s += pv.x + pv.y + pv.z + pv.w;
      sq += uv.x * uv.x + uv.y * uv.y + uv.z * uv.z + uv.w * uv.w;
      sq += pv.x * pv.x + pv.y * pv.y + pv.z * pv.z + pv.w * pv.w;
    }
    s = wsum64(s);
    sq = wsum64(sq);
    const float mu = s * (1.f / 2048.f);
    const float rstd = rsqrtf(sq * (1.f / 2048.f) - mu * mu + EPS_LN);
    if (lane == 0) { stat_mu[rl] = mu; stat_rs[rl] = rstd; }

    // ---- aux gate for this row (A=256, F8=8, all fp32 VALU) ----
    const float4 av = reinterpret_cast<const float4*>(aux + (size_t)row * 256)[lane];
    float as = av.x + av.y + av.z + av.w;
    float asq = av.x * av.x + av.y * av.y + av.z * av.z + av.w * av.w;
    as = wsum64(as);
    asq = wsum64(asq);
    const float amu = as * (1.f / 256.f);
    const float arstd = rsqrtf(asq * (1.f / 256.f) - amu * amu + EPS_LN);
    float aa[4];
    aa[0] = fmaxf((av.x - amu) * arstd * agv4.x + abv4.x, 0.f);
    aa[1] = fmaxf((av.y - amu) * arstd * agv4.y + abv4.y, 0.f);
    aa[2] = fmaxf((av.z - amu) * arstd * agv4.z + abv4.z, 0.f);
    aa[3] = fmaxf((av.w - amu) * arstd * agv4.w + abv4.w, 0.f);
    float pf[8];
#pragma unroll
    for (int f = 0; f < 8; ++f) pf[f] = 0.f;
#pragma unroll
    for (int t = 0; t < 4; ++t) {
      const float4* wr = reinterpret_cast<const float4*>(W_aux + (((size_t)lane << 2) + t) * 8);
      float4 wa = wr[0], wb = wr[1];
      pf[0] += aa[t] * wa.x; pf[1] += aa[t] * wa.y;
      pf[2] += aa[t] * wa.z; pf[3] += aa[t] * wa.w;
      pf[4] += aa[t] * wb.x; pf[5] += aa[t] * wb.y;
      pf[6] += aa[t] * wb.z; pf[7] += aa[t] * wb.w;
    }
    // Reduce all 8 outputs in parallel within 8-lane groups (24 shuffles),
    // select pf[lane&7], finish across groups (3), sigmoid once, sum f (3).
#pragma unroll
    for (int f = 0; f < 8; ++f) {
      pf[f] += __shfl_xor(pf[f], 1);
      pf[f] += __shfl_xor(pf[f], 2);
      pf[f] += __shfl_xor(pf[f], 4);
    }
    float v01 = (lane & 1) ? pf[1] : pf[0];
    float v23 = (lane & 1) ? pf[3] : pf[2];
    float v45 = (lane & 1) ? pf[5] : pf[4];
    float v67 = (lane & 1) ? pf[7] : pf[6];
    float v03 = (lane & 2) ? v23 : v01;
    float v47 = (lane & 2) ? v67 : v45;
    float v = (lane & 4) ? v47 : v03;
    v += __shfl_xor(v, 8);
    v += __shfl_xor(v, 16);
    v += __shfl_xor(v, 32);               // v = full-sum pf[lane&7]
    float sg = sigmoidf_(v + bauxl);
    sg += __shfl_xor(sg, 1);
    sg += __shfl_xor(sg, 2);
    sg += __shfl_xor(sg, 4);              // sum of 8 sigmoids
    const float agv = sg * 0.125f;
    if (i == 0) auxg0 = agv;
    else if (i == 1) auxg1 = agv;
    else if (i == 2) auxg2 = agv;
    else auxg3 = agv;
  }

  __syncthreads();

  // ------------- phase 2: k-split MFMA, normalize-on-reload ----------------
  // Wave w owns k in [512w, 512w+512): waves 0,1 read unary; 2,3 read pair.
  // A-frag: lane holds act[m = lane&15][k = (w*16+kb)*32 + (lane>>4)*8 + j].
  const int m = lane & 15;
  const int q = lane >> 4;
  const float mu = stat_mu[m];
  const float rs = stat_rs[m];
  const float nmr = -mu * rs;

  const float* srcp = (w < 2) ? unary : pair;
  const float* rowp = srcp + (size_t)(base + m) * 1024 + ((w & 1) << 9) + (q << 3);
  const float* gp = ln_g + (w << 9) + (q << 3);
  const float* bp = ln_b + (w << 9) + (q << 3);
  const unsigned short* wfp = wfrag + ((size_t)((w << 4) * 64 + lane) << 3);

  f32x4 acc[4] = {{0.f,0.f,0.f,0.f},{0.f,0.f,0.f,0.f},
                  {0.f,0.f,0.f,0.f},{0.f,0.f,0.f,0.f}};
#pragma unroll
  for (int kb = 0; kb < 16; ++kb) {
    const float4 x0 = *reinterpret_cast<const float4*>(rowp + (kb << 5));
    const float4 x1 = *reinterpret_cast<const float4*>(rowp + (kb << 5) + 4);
    const float4 g0 = *reinterpret_cast<const float4*>(gp + (kb << 5));
    const float4 g1 = *reinterpret_cast<const float4*>(gp + (kb << 5) + 4);
    const float4 b0 = *reinterpret_cast<const float4*>(bp + (kb << 5));
    const float4 b1 = *reinterpret_cast<const float4*>(bp + (kb << 5) + 4);
    short8 af;
    af[0] = nrm1(x0.x, g0.x, b0.x, rs, nmr);
    af[1] = nrm1(x0.y, g0.y, b0.y, rs, nmr);
    af[2] = nrm1(x0.z, g0.z, b0.z, rs, nmr);
    af[3] = nrm1(x0.w, g0.w, b0.w, rs, nmr);
    af[4] = nrm1(x1.x, g1.x, b1.x, rs, nmr);
    af[5] = nrm1(x1.y, g1.y, b1.y, rs, nmr);
    af[6] = nrm1(x1.z, g1.z, b1.z, rs, nmr);
    af[7] = nrm1(x1.w, g1.w, b1.w, rs, nmr);
#pragma unroll
    for (int nt = 0; nt < 4; ++nt) {
      const short8 bf = *reinterpret_cast<const short8*>(
          wfp + (size_t)nt * 32768 + (kb << 9));
      acc[nt] = __builtin_amdgcn_mfma_f32_16x16x32_bf16(af, bf, acc[nt], 0, 0, 0);
    }
  }

  // Partial D tiles to LDS: D[mrow = q*4+reg][f = nt*16 + m] for this wave's k.
#pragma unroll
  for (int nt = 0; nt < 4; ++nt)
#pragma unroll
    for (int r = 0; r < 4; ++r)
      part[w][(q << 2) + r][(nt << 4) + m] = acc[nt][r];

  __syncthreads();

  // ------------- epilogue: reduce partials, gates, scale pair --------------
  // Lane handles row rl = w*4 + q, f-quad f0 = 4m.
  const int rl = (w << 2) + q;
  const int f0 = m << 2;
  const float4 p0 = *reinterpret_cast<const float4*>(&part[0][rl][f0]);
  const float4 p1 = *reinterpret_cast<const float4*>(&part[1][rl][f0]);
  const float4 p2 = *reinterpret_cast<const float4*>(&part[2][rl][f0]);
  const float4 p3 = *reinterpret_cast<const float4*>(&part[3][rl][f0]);
  const float4 blv = reinterpret_cast<const float4*>(b_lin)[m];
  float sgs = sigmoidf_(p0.x + p1.x + p2.x + p3.x + blv.x)
            + sigmoidf_(p0.y + p1.y + p2.y + p3.y + blv.y)
            + sigmoidf_(p0.z + p1.z + p2.z + p3.z + blv.z)
            + sigmoidf_(p0.w + p1.w + p2.w + p3.w + blv.w);
  sgs += __shfl_xor(sgs, 1);
  sgs += __shfl_xor(sgs, 2);
  sgs += __shfl_xor(sgs, 4);
  sgs += __shfl_xor(sgs, 8);            // sum over all 64 f
  const float gate = sgs * (1.f / 64.f);
  const float auxg_r = (q == 0) ? auxg0 : (q == 1) ? auxg1
                     : (q == 2) ? auxg2 : auxg3;
  const float logit = gw[0] * rsigf(gate) + agw[0] * rsigf(auxg_r);
  const float g = sigmoidf_(logit) * auxw[base + rl];
  if (m == 0) out_g[base + rl] = g;

#pragma unroll
  for (int i = 0; i < 4; ++i) {
    const float gi = __shfl(g, i << 4);   // lane 16i holds row w*4+i's g
    const int row = base + (w << 2) + i;
    const float4* pp = reinterpret_cast<const float4*>(pair + (size_t)row * 1024);
    float4* oo = reinterpret_cast<float4*>(out + (size_t)row * 1024);
#pragma unroll
    for (int j = 0; j < 4; ++j) {
      float4 pv = pp[lane + (j << 6)];
      pv.x *= gi; pv.y *= gi; pv.z *= gi; pv.w *= gi;
      oo[lane + (j << 6)] = pv;
    }
  }
}

extern "C" void kernel_launch(void* const* d_in, const int* in_sizes, int n_in,
                              void* d_out, int out_size, void* d_ws, size_t ws_size,
                              hipStream_t stream) {
  const float* unary = (const float*)d_in[0];
  const float* pair  = (const float*)d_in[1];
  const float* aux   = (const float*)d_in[2];
  const float* auxw  = (const float*)d_in[3];
  const float* ln_g  = (const float*)d_in[4];
  const float* ln_b  = (const float*)d_in[5];
  const float* W     = (const float*)d_in[6];
  const float* b     = (const float*)d_in[7];
  const float* ln_ag = (const float*)d_in[8];
  const float* ln_ab = (const float*)d_in[9];
  const float* W_aux = (const float*)d_in[10];
  const float* b_aux = (const float*)d_in[11];
  const float* gw    = (const float*)d_in[12];
  const float* agw   = (const float*)d_in[13];

  const int N = in_sizes[3];            // 32768
  unsigned short* wfrag = (unsigned short*)d_ws;   // 256 KB bf16 W fragments
  float* out = (float*)d_out;
  float* out_g = out + (size_t)N * 1024;

  prep_wfrag<<<256, 64, 0, stream>>>(W, wfrag);
  fused_main<<<N / 16, 256, 0, stream>>>(unary, pair, aux, auxw, ln_g, ln_b, b,
                                         ln_ag, ln_ab, W_aux, b_aux, gw, agw,
                                         wfrag, out, out_g);
}

// Round 2
// 425.384 us; speedup vs baseline: 1.1284x; 1.0245x over previous
//
#include <hip/hip_runtime.h>
#include <math.h>

// MessagePassingUnitGatingWithRelnessLogits fused kernel, MI355X (gfx950).
// N=32768 rows; D=1024 (paired=2048); A=256; FD=64; F8=8.
// Block = 16 rows, 256 threads (4 waves).
// v3: ALL LayerNorm statistics (main + aux) computed via MFMA with a ones-B
//     fragment -- zero cross-lane shuffle chains in phase 1. Aux-gate GEMM
//     also via MFMA (prepped W_aux fragment). Wave w owns k-quarter
//     [512w,512w+512) of all 16 rows in A-fragment layout for BOTH the stat
//     pass and the GEMM pass, so phase-2 reloads are L1/L2 re-hits.

#define EPS_LN 1e-5f

typedef __attribute__((ext_vector_type(8))) short short8;   // 8 x bf16 (4 VGPRs)
typedef __attribute__((ext_vector_type(4))) float f32x4;    // MFMA accumulator

__device__ __forceinline__ unsigned short f2bf(float f) {
  unsigned int u = __float_as_uint(f);
  u += 0x7FFFu + ((u >> 16) & 1u);      // round-to-nearest-even
  return (unsigned short)(u >> 16);
}

// pack two fp32 -> one u32 of 2 x bf16 (RNE), low half = a
__device__ __forceinline__ unsigned pkbf2(float a, float b) {
  unsigned ua = __float_as_uint(a), ub = __float_as_uint(b);
  ua += 0x7FFFu + ((ua >> 16) & 1u);
  ub += 0x7FFFu + ((ub >> 16) & 1u);
  return (ub & 0xFFFF0000u) | (ua >> 16);
}

union S8U { unsigned u[4]; short8 v; };

__device__ __forceinline__ short8 pack8(float x0, float x1, float x2, float x3,
                                        float x4, float x5, float x6, float x7) {
  S8U r;
  r.u[0] = pkbf2(x0, x1); r.u[1] = pkbf2(x2, x3);
  r.u[2] = pkbf2(x4, x5); r.u[3] = pkbf2(x6, x7);
  return r.v;
}

__device__ __forceinline__ short8 ones8() {
  S8U r; r.u[0] = r.u[1] = r.u[2] = r.u[3] = 0x3F803F80u;  // bf16 1.0 pairs
  return r.v;
}

__device__ __forceinline__ float sigmoidf_(float x) {
  return 1.0f / (1.0f + __expf(-x));
}

// reverse_sigmoid forward: clip to [0.001,0.999], then logit
__device__ __forceinline__ float rsigf(float x) {
  float y = fminf(fmaxf(x, 0.001f), 0.999f);
  return logf(y) - log1pf(-y);
}

// normalize one element: relu -> LN affine -> relu -> bf16
__device__ __forceinline__ short nrm1(float x, float g, float b,
                                      float rs, float nmr) {
  float t = fmaxf(x, 0.f);
  float n = fmaf(t, rs, nmr);           // (t - mu) * rstd
  float z = fmaxf(fmaf(n, g, b), 0.f);
  return (short)f2bf(z);
}

// ---------------------------------------------------------------------------
// Prep: W [2048][64] fp32 -> bf16 B-fragments in MFMA operand order, plus
// W_aux [256][8] -> bf16 B-fragments (cols 8..15 zero).
// Main: frag[((ntile*64 + kb)*64 + lane)*8 + j] = bf16(W[k][f]),
//   f = ntile*16 + (lane&15), k = kb*32 + (lane>>4)*8 + j.
// Aux (blocks 256..263): auxfrag[((kb*64)+lane)*8 + j] = bf16(W_aux[k][f]) or 0.
// grid = 264 blocks x 64 threads.
// ---------------------------------------------------------------------------
__global__ void prep_frags(const float* __restrict__ W,
                           const float* __restrict__ W_aux,
                           unsigned short* __restrict__ wfrag) {
  const int lane = threadIdx.x;
  const int b = blockIdx.x;
  unsigned short tmp[8];
  if (b < 256) {
    const int ntile = b >> 6;
    const int kb = b & 63;
    const int f = (ntile << 4) + (lane & 15);
    const int kbase = (kb << 5) + ((lane >> 4) << 3);
#pragma unroll
    for (int j = 0; j < 8; ++j) tmp[j] = f2bf(W[(size_t)(kbase + j) * 64 + f]);
    ushort4* dst = reinterpret_cast<ushort4*>(wfrag + (((size_t)b * 64 + lane) << 3));
    dst[0] = make_ushort4(tmp[0], tmp[1], tmp[2], tmp[3]);
    dst[1] = make_ushort4(tmp[4], tmp[5], tmp[6], tmp[7]);
  } else {
    const int kb = b - 256;             // 0..7
    const int f = lane & 15;
    const int kbase = (kb << 5) + ((lane >> 4) << 3);
#pragma unroll
    for (int j = 0; j < 8; ++j)
      tmp[j] = (f < 8) ? f2bf(W_aux[(size_t)(kbase + j) * 8 + f]) : (unsigned short)0;
    ushort4* dst = reinterpret_cast<ushort4*>(wfrag + 131072 +
                                              (((size_t)kb * 64 + lane) << 3));
    dst[0] = make_ushort4(tmp[0], tmp[1], tmp[2], tmp[3]);
    dst[1] = make_ushort4(tmp[4], tmp[5], tmp[6], tmp[7]);
  }
}

// ---------------------------------------------------------------------------
// Main fused kernel.
// ---------------------------------------------------------------------------
__global__ void __launch_bounds__(256, 4) fused_main(
    const float* __restrict__ unary, const float* __restrict__ pair,
    const float* __restrict__ aux, const float* __restrict__ auxw,
    const float* __restrict__ ln_g, const float* __restrict__ ln_b,
    const float* __restrict__ b_lin,
    const float* __restrict__ ln_ag, const float* __restrict__ ln_ab,
    const float* __restrict__ b_aux,
    const float* __restrict__ gw, const float* __restrict__ agw,
    const unsigned short* __restrict__ wfrag,
    float* __restrict__ out, float* __restrict__ out_g) {
  // Cross-wave f32 partial tiles [wave][row][f], f-stride 68 to avoid aliasing.
  __shared__ float part[4][16][68];     // 17408 B
  __shared__ float auxpart[4][16][8];   // 2048 B
  __shared__ float4 statp[4][16];       // per-wave (S, Q, Sa, Qa) per row, 1 KB

  const int tid = threadIdx.x;
  const int w = tid >> 6;     // wave 0..3
  const int lane = tid & 63;
  const int base = blockIdx.x << 4;
  const int m = lane & 15;    // A row (block row) in fragment layout
  const int q = lane >> 4;    // k sub-chunk within 32-k tile

  // Wave k-quarter: w0,w1 -> unary halves 0,1; w2,w3 -> pair halves 0,1.
  const float* srcp = (w < 2) ? unary : pair;
  const float* arow = srcp + (size_t)(base + m) * 1024 + ((w & 1) << 9) + (q << 3);
  const float* axrow = aux + (size_t)(base + m) * 256 + (w << 6) + (q << 3);

  const short8 onef = ones8();

  // ------------- phase 1: stat MFMAs (Σx, Σx² for main; Σa, Σa² for aux) ----
  f32x4 aS = {0.f,0.f,0.f,0.f}, aQ = {0.f,0.f,0.f,0.f};
  f32x4 sS = {0.f,0.f,0.f,0.f}, sQ = {0.f,0.f,0.f,0.f};
  float axv[16];              // retained raw aux values (this lane's 16 k's)

#pragma unroll
  for (int kb = 0; kb < 2; ++kb) {
    const float4 x0 = *reinterpret_cast<const float4*>(axrow + (kb << 5));
    const float4 x1 = *reinterpret_cast<const float4*>(axrow + (kb << 5) + 4);
    axv[kb * 8 + 0] = x0.x; axv[kb * 8 + 1] = x0.y;
    axv[kb * 8 + 2] = x0.z; axv[kb * 8 + 3] = x0.w;
    axv[kb * 8 + 4] = x1.x; axv[kb * 8 + 5] = x1.y;
    axv[kb * 8 + 6] = x1.z; axv[kb * 8 + 7] = x1.w;
    const short8 a = pack8(x0.x, x0.y, x0.z, x0.w, x1.x, x1.y, x1.z, x1.w);
    const short8 a2 = pack8(x0.x * x0.x, x0.y * x0.y, x0.z * x0.z, x0.w * x0.w,
                            x1.x * x1.x, x1.y * x1.y, x1.z * x1.z, x1.w * x1.w);
    sS = __builtin_amdgcn_mfma_f32_16x16x32_bf16(a, onef, sS, 0, 0, 0);
    sQ = __builtin_amdgcn_mfma_f32_16x16x32_bf16(a2, onef, sQ, 0, 0, 0);
  }

#pragma unroll
  for (int kb = 0; kb < 16; ++kb) {
    const float4 x0 = *reinterpret_cast<const float4*>(arow + (kb << 5));
    const float4 x1 = *reinterpret_cast<const float4*>(arow + (kb << 5) + 4);
    const float r0 = fmaxf(x0.x, 0.f), r1 = fmaxf(x0.y, 0.f);
    const float r2 = fmaxf(x0.z, 0.f), r3 = fmaxf(x0.w, 0.f);
    const float r4 = fmaxf(x1.x, 0.f), r5 = fmaxf(x1.y, 0.f);
    const float r6 = fmaxf(x1.z, 0.f), r7 = fmaxf(x1.w, 0.f);
    const short8 a = pack8(r0, r1, r2, r3, r4, r5, r6, r7);
    const short8 a2 = pack8(r0 * r0, r1 * r1, r2 * r2, r3 * r3,
                            r4 * r4, r5 * r5, r6 * r6, r7 * r7);
    aS = __builtin_amdgcn_mfma_f32_16x16x32_bf16(a, onef, aS, 0, 0, 0);
    aQ = __builtin_amdgcn_mfma_f32_16x16x32_bf16(a2, onef, aQ, 0, 0, 0);
  }

  // D layout: col = lane&15 (all cols equal with ones-B), row = q*4 + reg.
  // Column-lane 0 of each quad publishes its 4 rows' partials.
  if ((lane & 15) == 0) {
    statp[w][(q << 2) + 0] = make_float4(aS[0], aQ[0], sS[0], sQ[0]);
    statp[w][(q << 2) + 1] = make_float4(aS[1], aQ[1], sS[1], sQ[1]);
    statp[w][(q << 2) + 2] = make_float4(aS[2], aQ[2], sS[2], sQ[2]);
    statp[w][(q << 2) + 3] = make_float4(aS[3], aQ[3], sS[3], sQ[3]);
  }
  __syncthreads();

  // Per-lane stats for row m (needed for phase-2 normalize).
  const float4 s0 = statp[0][m], s1 = statp[1][m], s2 = statp[2][m], s3 = statp[3][m];
  const float S  = s0.x + s1.x + s2.x + s3.x;
  const float Q  = s0.y + s1.y + s2.y + s3.y;
  const float Sa = s0.z + s1.z + s2.z + s3.z;
  const float Qa = s0.w + s1.w + s2.w + s3.w;
  const float mu = S * (1.f / 2048.f);
  const float rs = rsqrtf(Q * (1.f / 2048.f) - mu * mu + EPS_LN);
  const float nmr = -mu * rs;
  const float amu = Sa * (1.f / 256.f);
  const float ars = rsqrtf(Qa * (1.f / 256.f) - amu * amu + EPS_LN);
  const float anmr = -amu * ars;

  // ------------- phase 2: main GEMM (reload L1/L2-hot) + aux GEMM ----------
  const float* gp = ln_g + (w << 9) + (q << 3);
  const float* bp = ln_b + (w << 9) + (q << 3);
  const unsigned short* wfp = wfrag + ((size_t)((w << 4) * 64 + lane) << 3);

  f32x4 acc[4] = {{0.f,0.f,0.f,0.f},{0.f,0.f,0.f,0.f},
                  {0.f,0.f,0.f,0.f},{0.f,0.f,0.f,0.f}};
#pragma unroll
  for (int kb = 0; kb < 16; ++kb) {
    const float4 x0 = *reinterpret_cast<const float4*>(arow + (kb << 5));
    const float4 x1 = *reinterpret_cast<const float4*>(arow + (kb << 5) + 4);
    const float4 g0 = *reinterpret_cast<const float4*>(gp + (kb << 5));
    const float4 g1 = *reinterpret_cast<const float4*>(gp + (kb << 5) + 4);
    const float4 b0 = *reinterpret_cast<const float4*>(bp + (kb << 5));
    const float4 b1 = *reinterpret_cast<const float4*>(bp + (kb << 5) + 4);
    short8 af;
    af[0] = nrm1(x0.x, g0.x, b0.x, rs, nmr);
    af[1] = nrm1(x0.y, g0.y, b0.y, rs, nmr);
    af[2] = nrm1(x0.z, g0.z, b0.z, rs, nmr);
    af[3] = nrm1(x0.w, g0.w, b0.w, rs, nmr);
    af[4] = nrm1(x1.x, g1.x, b1.x, rs, nmr);
    af[5] = nrm1(x1.y, g1.y, b1.y, rs, nmr);
    af[6] = nrm1(x1.z, g1.z, b1.z, rs, nmr);
    af[7] = nrm1(x1.w, g1.w, b1.w, rs, nmr);
#pragma unroll
    for (int nt = 0; nt < 4; ++nt) {
      const short8 bf = *reinterpret_cast<const short8*>(
          wfp + (size_t)nt * 32768 + (kb << 9));
      acc[nt] = __builtin_amdgcn_mfma_f32_16x16x32_bf16(af, bf, acc[nt], 0, 0, 0);
    }
  }

  // Aux GEMM from retained registers (no reload, no shuffles).
  const float* agp = ln_ag + (w << 6) + (q << 3);
  const float* abp = ln_ab + (w << 6) + (q << 3);
  const unsigned short* afp = wfrag + 131072;
  f32x4 acca = {0.f,0.f,0.f,0.f};
#pragma unroll
  for (int kb = 0; kb < 2; ++kb) {
    const float4 g0 = *reinterpret_cast<const float4*>(agp + (kb << 5));
    const float4 g1 = *reinterpret_cast<const float4*>(agp + (kb << 5) + 4);
    const float4 b0 = *reinterpret_cast<const float4*>(abp + (kb << 5));
    const float4 b1 = *reinterpret_cast<const float4*>(abp + (kb << 5) + 4);
    short8 af;
    af[0] = (short)f2bf(fmaxf(fmaf(fmaf(axv[kb*8+0], ars, anmr), g0.x, b0.x), 0.f));
    af[1] = (short)f2bf(fmaxf(fmaf(fmaf(axv[kb*8+1], ars, anmr), g0.y, b0.y), 0.f));
    af[2] = (short)f2bf(fmaxf(fmaf(fmaf(axv[kb*8+2], ars, anmr), g0.z, b0.z), 0.f));
    af[3] = (short)f2bf(fmaxf(fmaf(fmaf(axv[kb*8+3], ars, anmr), g0.w, b0.w), 0.f));
    af[4] = (short)f2bf(fmaxf(fmaf(fmaf(axv[kb*8+4], ars, anmr), g1.x, b1.x), 0.f));
    af[5] = (short)f2bf(fmaxf(fmaf(fmaf(axv[kb*8+5], ars, anmr), g1.y, b1.y), 0.f));
    af[6] = (short)f2bf(fmaxf(fmaf(fmaf(axv[kb*8+6], ars, anmr), g1.z, b1.z), 0.f));
    af[7] = (short)f2bf(fmaxf(fmaf(fmaf(axv[kb*8+7], ars, anmr), g1.w, b1.w), 0.f));
    const short8 bf = *reinterpret_cast<const short8*>(
        afp + ((size_t)(((w << 1) + kb) * 64 + lane) << 3));
    acca = __builtin_amdgcn_mfma_f32_16x16x32_bf16(af, bf, acca, 0, 0, 0);
  }

  // Partial D tiles to LDS: D[row = q*4+reg][f = nt*16 + m] for this k-quarter.
#pragma unroll
  for (int nt = 0; nt < 4; ++nt)
#pragma unroll
    for (int r = 0; r < 4; ++r)
      part[w][(q << 2) + r][(nt << 4) + m] = acc[nt][r];
  if (m < 8) {
#pragma unroll
    for (int r = 0; r < 4; ++r)
      auxpart[w][(q << 2) + r][m] = acca[r];
  }
  __syncthreads();

  // ------------- epilogue: reduce partials, gates, scale pair --------------
  // Lane handles row rl = w*4 + q, main f-quad f0 = 4m; aux f = m&7.
  const int rl = (w << 2) + q;
  const int f0 = m << 2;
  const float4 p0 = *reinterpret_cast<const float4*>(&part[0][rl][f0]);
  const float4 p1 = *reinterpret_cast<const float4*>(&part[1][rl][f0]);
  const float4 p2 = *reinterpret_cast<const float4*>(&part[2][rl][f0]);
  const float4 p3 = *reinterpret_cast<const float4*>(&part[3][rl][f0]);
  const float4 blv = reinterpret_cast<const float4*>(b_lin)[m];
  float sgs = sigmoidf_(p0.x + p1.x + p2.x + p3.x + blv.x)
            + sigmoidf_(p0.y + p1.y + p2.y + p3.y + blv.y)
            + sigmoidf_(p0.z + p1.z + p2.z + p3.z + blv.z)
            + sigmoidf_(p0.w + p1.w + p2.w + p3.w + blv.w);
  sgs += __shfl_xor(sgs, 1);
  sgs += __shfl_xor(sgs, 2);
  sgs += __shfl_xor(sgs, 4);
  sgs += __shfl_xor(sgs, 8);            // sum over all 64 f
  const float gate = sgs * (1.f / 64.f);

  const int fa = m & 7;
  float av4 = auxpart[0][rl][fa] + auxpart[1][rl][fa] +
              auxpart[2][rl][fa] + auxpart[3][rl][fa];
  float axs = sigmoidf_(av4 + b_aux[fa]);
  axs = (m < 8) ? axs : 0.f;
  axs += __shfl_xor(axs, 1);
  axs += __shfl_xor(axs, 2);
  axs += __shfl_xor(axs, 4);
  axs += __shfl_xor(axs, 8);            // sum of 8 aux sigmoids (all m-lanes)
  const float auxg = axs * 0.125f;

  const float logit = gw[0] * rsigf(gate) + agw[0] * rsigf(auxg);
  const float g = sigmoidf_(logit) * auxw[base + rl];
  if (m == 0) out_g[base + rl] = g;

#pragma unroll
  for (int i = 0; i < 4; ++i) {
    const float gi = __shfl(g, (i << 4));   // lane 16i holds row w*4+i's g
    const int row = base + (w << 2) + i;
    const float4* pp = reinterpret_cast<const float4*>(pair + (size_t)row * 1024);
    float4* oo = reinterpret_cast<float4*>(out + (size_t)row * 1024);
#pragma unroll
    for (int j = 0; j < 4; ++j) {
      float4 pv = pp[lane + (j << 6)];
      pv.x *= gi; pv.y *= gi; pv.z *= gi; pv.w *= gi;
      oo[lane + (j << 6)] = pv;
    }
  }
}

extern "C" void kernel_launch(void* const* d_in, const int* in_sizes, int n_in,
                              void* d_out, int out_size, void* d_ws, size_t ws_size,
                              hipStream_t stream) {
  const float* unary = (const float*)d_in[0];
  const float* pair  = (const float*)d_in[1];
  const float* aux   = (const float*)d_in[2];
  const float* auxw  = (const float*)d_in[3];
  const float* ln_g  = (const float*)d_in[4];
  const float* ln_b  = (const float*)d_in[5];
  const float* W     = (const float*)d_in[6];
  const float* b     = (const float*)d_in[7];
  const float* ln_ag = (const float*)d_in[8];
  const float* ln_ab = (const float*)d_in[9];
  const float* W_aux = (const float*)d_in[10];
  const float* b_aux = (const float*)d_in[11];
  const float* gw    = (const float*)d_in[12];
  const float* agw   = (const float*)d_in[13];

  const int N = in_sizes[3];            // 32768
  unsigned short* wfrag = (unsigned short*)d_ws;   // 256 KB main + 8 KB aux frags
  float* out = (float*)d_out;
  float* out_g = out + (size_t)N * 1024;

  prep_frags<<<264, 64, 0, stream>>>(W, W_aux, wfrag);
  fused_main<<<N / 16, 256, 0, stream>>>(unary, pair, aux, auxw, ln_g, ln_b, b,
                                         ln_ag, ln_ab, b_aux, gw, agw,
                                         wfrag, out, out_g);
}